// Round 1
// baseline (1477.918 us; speedup 1.0000x reference)
//
#include <hip/hip_runtime.h>
#include <hip/hip_bf16.h>
#include <math.h>

typedef unsigned short u16;
typedef __bf16 bf16x8 __attribute__((ext_vector_type(8)));
typedef float f32x4 __attribute__((ext_vector_type(4)));

#define B_  2
#define S_  2048
#define D_  4096
#define H_  32
#define HD_ 128

__device__ __forceinline__ unsigned rne_bf16(float x) {
  unsigned u = __float_as_uint(x);
  return (u + 0x7fffu + ((u >> 16) & 1u)) >> 16;
}

__device__ __forceinline__ void async16(void* lds, const void* g) {
  __builtin_amdgcn_global_load_lds(
      (__attribute__((address_space(1))) void*)(g),
      (__attribute__((address_space(3))) void*)(lds), 16, 0, 0);
}

// ---------------------------------------------------------------- convert
__global__ __launch_bounds__(256) void convert_bf16(
    const float* __restrict__ src, u16* __restrict__ dst, int n8) {
  int i = blockIdx.x * 256 + threadIdx.x;
  if (i >= n8) return;
  const float4* s = (const float4*)src + (size_t)i * 2;
  float4 a = s[0], b = s[1];
  uint4 o;
  o.x = rne_bf16(a.x) | (rne_bf16(a.y) << 16);
  o.y = rne_bf16(a.z) | (rne_bf16(a.w) << 16);
  o.z = rne_bf16(b.x) | (rne_bf16(b.y) << 16);
  o.w = rne_bf16(b.z) | (rne_bf16(b.w) << 16);
  ((uint4*)dst)[i] = o;
}

// ---------------------------------------------------------------- GEMM (A row-major MxK, B row-major NxK, C = A*B^T)
// MODE 1: RoPE epilogue -> outB[bh][s][d]   (Q or K)
// MODE 3: transpose epilogue -> outB[bh][d][s]  (V^T)
// MODE 4: fp32 epilogue -> outF[m][n]          (final projection)
template <int MODE>
__global__ __launch_bounds__(256) void gemm_bt(
    const u16* __restrict__ A, const u16* __restrict__ Bw,
    u16* __restrict__ outB, float* __restrict__ outF,
    const float* __restrict__ fc, const float* __restrict__ fs) {
  __shared__ u16 As[128 * 32];
  __shared__ u16 Bs[128 * 32];
  const int tid  = threadIdx.x;
  const int lane = tid & 63;
  const int wave = tid >> 6;
  const int lm   = lane & 15, quad = lane >> 4;
  const int m0 = blockIdx.x * 128, n0 = blockIdx.y * 128;
  const int mr = (wave >> 1) * 64, nc = (wave & 1) * 64;
  const int K = 4096;

  // staging chunks: LDS slot c (16B) holds global chunk (row=c>>2, kc=(c&3)^((c>>4)&3))
  const int c0 = tid, c1 = tid + 256;
  const int r0 = c0 >> 2, kc0 = ((c0 & 3) ^ ((c0 >> 4) & 3)) * 8;
  const int r1 = c1 >> 2, kc1 = ((c1 & 3) ^ ((c1 >> 4) & 3)) * 8;
  const u16* Ag0 = A + (size_t)(m0 + r0) * K + kc0;
  const u16* Ag1 = A + (size_t)(m0 + r1) * K + kc1;
  const u16* Bg0 = Bw + (size_t)(n0 + r0) * K + kc0;
  const u16* Bg1 = Bw + (size_t)(n0 + r1) * K + kc1;

  const int koff = (quad ^ ((lm >> 2) & 3)) * 8;  // swizzled k-chunk offset for frag reads

  f32x4 acc[4][4] = {};

  for (int kb = 0; kb < K; kb += 32) {
    async16(&As[c0 * 8], Ag0 + kb);
    async16(&As[c1 * 8], Ag1 + kb);
    async16(&Bs[c0 * 8], Bg0 + kb);
    async16(&Bs[c1 * 8], Bg1 + kb);
    __syncthreads();
    bf16x8 af[4], bfr[4];
#pragma unroll
    for (int i = 0; i < 4; ++i) af[i] = *(const bf16x8*)&As[(mr + i * 16 + lm) * 32 + koff];
#pragma unroll
    for (int j = 0; j < 4; ++j) bfr[j] = *(const bf16x8*)&Bs[(nc + j * 16 + lm) * 32 + koff];
#pragma unroll
    for (int i = 0; i < 4; ++i)
#pragma unroll
      for (int j = 0; j < 4; ++j)
        acc[i][j] = __builtin_amdgcn_mfma_f32_16x16x32_bf16(af[i], bfr[j], acc[i][j], 0, 0, 0);
    __syncthreads();
  }

  if (MODE == 1) {  // RoPE -> [bh][s][d]
#pragma unroll
    for (int i = 0; i < 4; ++i) {
      const int mbase = m0 + mr + i * 16 + quad * 4;
#pragma unroll
      for (int j = 0; j < 4; ++j) {
        const int n = n0 + nc + j * 16 + lm;
        const int h = n >> 7, d = n & 127, ir = d >> 1;
#pragma unroll
        for (int r = 0; r < 4; ++r) {
          const int m = mbase + r;
          const int s = m & (S_ - 1);
          const int bb = m >> 11;
          float v = acc[i][j][r];
          float p = __shfl_xor(v, 1);
          float cv = fc[s * (HD_ / 2) + ir];
          float sv = fs[s * (HD_ / 2) + ir];
          float o = ((lane & 1) == 0) ? (v * cv - p * sv) : (p * sv + v * cv);
          float po = __shfl_xor(o, 1);
          if ((lane & 1) == 0) {
            unsigned pkt = rne_bf16(o) | (rne_bf16(po) << 16);
            size_t idx = (((size_t)(bb * H_ + h) * S_ + s) * HD_ + d) >> 1;
            ((unsigned*)outB)[idx] = pkt;
          }
        }
      }
    }
  } else if (MODE == 3) {  // V^T -> [bh][d][s]
#pragma unroll
    for (int i = 0; i < 4; ++i) {
      const int mbase = m0 + mr + i * 16 + quad * 4;
      const int s0 = mbase & (S_ - 1);
      const int bb = mbase >> 11;
#pragma unroll
      for (int j = 0; j < 4; ++j) {
        const int n = n0 + nc + j * 16 + lm;
        const int h = n >> 7, d = n & 127;
        uint2 pkt;
        pkt.x = rne_bf16(acc[i][j][0]) | (rne_bf16(acc[i][j][1]) << 16);
        pkt.y = rne_bf16(acc[i][j][2]) | (rne_bf16(acc[i][j][3]) << 16);
        size_t idx = ((size_t)(bb * H_ + h) * HD_ + d) * S_ + s0;
        *(uint2*)&outB[idx] = pkt;
      }
    }
  } else {  // fp32 out [m][n]
#pragma unroll
    for (int i = 0; i < 4; ++i) {
      const int mbase = m0 + mr + i * 16 + quad * 4;
#pragma unroll
      for (int j = 0; j < 4; ++j) {
        const int n = n0 + nc + j * 16 + lm;
#pragma unroll
        for (int r = 0; r < 4; ++r) outF[(size_t)(mbase + r) * D_ + n] = acc[i][j][r];
      }
    }
  }
}

// ---------------------------------------------------------------- flash attention
// grid (32 q-tiles, 64 bh). 4 waves x 16 q-rows. BQ=BK=64, HD=128.
__global__ __launch_bounds__(256) void flash_attn(
    const u16* __restrict__ Qb, const u16* __restrict__ Kb,
    const u16* __restrict__ Vtb, u16* __restrict__ attn) {
  __shared__ u16 Qs[64 * 136];
  __shared__ u16 Ks[64 * 136];
  __shared__ u16 Vts[128 * 72];
  __shared__ u16 Ps[64 * 72];

  const int tid = threadIdx.x;
  const int lane = tid & 63, wave = tid >> 6;
  const int lm = lane & 15, quad = lane >> 4;
  const int qt = gridDim.x - 1 - blockIdx.x;  // heavy tiles first
  const int bh = blockIdx.y;
  const int bb = bh >> 5, h = bh & 31;

  const u16* Qg = Qb + ((size_t)bh * S_ + qt * 64) * HD_;
  const u16* Kg = Kb + (size_t)bh * S_ * HD_;
  const u16* Vg = Vtb + (size_t)bh * HD_ * S_;

  // stage Q tile (64 x 128)
#pragma unroll
  for (int it = 0; it < 4; ++it) {
    int c = tid + 256 * it;
    int row = c >> 4, col = (c & 15) * 8;
    uint4 v = *(const uint4*)(Qg + (size_t)row * HD_ + col);
    *(uint4*)&Qs[row * 136 + col] = v;
  }

  f32x4 accO[8] = {};
  float m_run[4], l_run[4];
#pragma unroll
  for (int r = 0; r < 4; ++r) { m_run[r] = -1e30f; l_run[r] = 0.f; }

  const float scale = 0.08838834764831845f;  // 1/sqrt(128)
  const int q_row_base = qt * 64 + wave * 16 + quad * 4;

  const int nkt = qt + 1;
  for (int kt = 0; kt < nkt; ++kt) {
    const int k0 = kt * 64;
    __syncthreads();
    // stage K tile (64 x 128)
#pragma unroll
    for (int it = 0; it < 4; ++it) {
      int c = tid + 256 * it;
      int row = c >> 4, col = (c & 15) * 8;
      uint4 v = *(const uint4*)(Kg + (size_t)(k0 + row) * HD_ + col);
      *(uint4*)&Ks[row * 136 + col] = v;
    }
    // stage V^T tile (128 x 64)
#pragma unroll
    for (int it = 0; it < 4; ++it) {
      int c = tid + 256 * it;
      int row = c >> 3, col = (c & 7) * 8;
      uint4 v = *(const uint4*)(Vg + (size_t)row * S_ + k0 + col);
      *(uint4*)&Vts[row * 72 + col] = v;
    }
    __syncthreads();

    // S = Q K^T (16 q-rows x 64 k-cols per wave)
    f32x4 sacc[4] = {};
#pragma unroll
    for (int dk = 0; dk < 4; ++dk) {
      bf16x8 aq = *(const bf16x8*)&Qs[(wave * 16 + lm) * 136 + dk * 32 + quad * 8];
#pragma unroll
      for (int j = 0; j < 4; ++j) {
        bf16x8 bk = *(const bf16x8*)&Ks[(j * 16 + lm) * 136 + dk * 32 + quad * 8];
        sacc[j] = __builtin_amdgcn_mfma_f32_16x16x32_bf16(aq, bk, sacc[j], 0, 0, 0);
      }
    }
    // scale + causal mask
    float sv[4][4];
#pragma unroll
    for (int j = 0; j < 4; ++j) {
      const int kk = k0 + j * 16 + lm;
#pragma unroll
      for (int r = 0; r < 4; ++r) {
        float v = sacc[j][r] * scale;
        if (kk > q_row_base + r) v = -1e30f;
        sv[j][r] = v;
      }
    }
    // online softmax per q-row
    float alpha[4];
#pragma unroll
    for (int r = 0; r < 4; ++r) {
      float rm = fmaxf(fmaxf(sv[0][r], sv[1][r]), fmaxf(sv[2][r], sv[3][r]));
      rm = fmaxf(rm, __shfl_xor(rm, 1));
      rm = fmaxf(rm, __shfl_xor(rm, 2));
      rm = fmaxf(rm, __shfl_xor(rm, 4));
      rm = fmaxf(rm, __shfl_xor(rm, 8));
      float mnew = fmaxf(m_run[r], rm);
      alpha[r] = __expf(m_run[r] - mnew);
      m_run[r] = mnew;
      float rs = 0.f;
#pragma unroll
      for (int j = 0; j < 4; ++j) {
        float pj = __expf(sv[j][r] - mnew);
        sv[j][r] = pj;
        rs += pj;
      }
      rs += __shfl_xor(rs, 1);
      rs += __shfl_xor(rs, 2);
      rs += __shfl_xor(rs, 4);
      rs += __shfl_xor(rs, 8);
      l_run[r] = l_run[r] * alpha[r] + rs;
    }
#pragma unroll
    for (int jd = 0; jd < 8; ++jd)
#pragma unroll
      for (int r = 0; r < 4; ++r) accO[jd][r] *= alpha[r];
    // P -> LDS (wave-private rows; no barrier needed)
#pragma unroll
    for (int j = 0; j < 4; ++j)
#pragma unroll
      for (int r = 0; r < 4; ++r)
        Ps[(wave * 16 + quad * 4 + r) * 72 + j * 16 + lm] = (u16)rne_bf16(sv[j][r]);
    // O += P V
#pragma unroll
    for (int ks = 0; ks < 2; ++ks) {
      bf16x8 ap = *(const bf16x8*)&Ps[(wave * 16 + lm) * 72 + ks * 32 + quad * 8];
#pragma unroll
      for (int jd = 0; jd < 8; ++jd) {
        bf16x8 bv = *(const bf16x8*)&Vts[(jd * 16 + lm) * 72 + ks * 32 + quad * 8];
        accO[jd] = __builtin_amdgcn_mfma_f32_16x16x32_bf16(ap, bv, accO[jd], 0, 0, 0);
      }
    }
  }

  // epilogue: normalize, write attn[b*S + s][h*HD + d] (bf16, paired u32 stores)
  const int srow = qt * 64 + wave * 16 + quad * 4;
#pragma unroll
  for (int r = 0; r < 4; ++r) {
    float inv = 1.0f / l_run[r];
    const size_t rowoff = (size_t)(bb * S_ + srow + r) * D_ + h * HD_;
#pragma unroll
    for (int jd = 0; jd < 8; ++jd) {
      float o = accO[jd][r] * inv;
      float po = __shfl_xor(o, 1);
      if ((lane & 1) == 0) {
        unsigned pkt = rne_bf16(o) | (rne_bf16(po) << 16);
        *(unsigned*)&attn[rowoff + jd * 16 + lm] = pkt;
      }
    }
  }
}

// ---------------------------------------------------------------- launch
extern "C" void kernel_launch(void* const* d_in, const int* in_sizes, int n_in,
                              void* d_out, int out_size, void* d_ws, size_t ws_size,
                              hipStream_t stream) {
  const float* x  = (const float*)d_in[0];
  const float* fc = (const float*)d_in[1];
  const float* fs = (const float*)d_in[2];
  // d_in[3] = mask (causal, handled analytically)
  const float* wq = (const float*)d_in[4];
  const float* wk = (const float*)d_in[5];
  const float* wv = (const float*)d_in[6];
  const float* wo = (const float*)d_in[7];
  float* out = (float*)d_out;

  char* ws = (char*)d_ws;
  const size_t SZ = (size_t)B_ * S_ * D_ * 2;  // 33.5 MB bf16 buffer
  u16* xb  = (u16*)(ws);            // x bf16; later aliased as attn output
  u16* wqb = (u16*)(ws + SZ);       // wq bf16; later aliased as wo bf16
  u16* wkb = (u16*)(ws + 2 * SZ);
  u16* wvb = (u16*)(ws + 3 * SZ);
  u16* Qb  = (u16*)(ws + 4 * SZ);
  u16* Kb  = (u16*)(ws + 5 * SZ);
  u16* Vtb = (u16*)(ws + 6 * SZ);   // total 224 MiB
  u16* attn = xb;
  u16* wob  = wqb;

  dim3 blk(256);
  const int n8 = (B_ * S_ * D_) / 8;  // 2097152
  convert_bf16<<<n8 / 256, blk, 0, stream>>>(x, xb, n8);
  convert_bf16<<<n8 / 256, blk, 0, stream>>>(wq, wqb, n8);
  convert_bf16<<<n8 / 256, blk, 0, stream>>>(wk, wkb, n8);
  convert_bf16<<<n8 / 256, blk, 0, stream>>>(wv, wvb, n8);

  dim3 g1(32, 32);
  gemm_bt<1><<<g1, blk, 0, stream>>>(xb, wqb, Qb, nullptr, fc, fs);
  gemm_bt<1><<<g1, blk, 0, stream>>>(xb, wkb, Kb, nullptr, fc, fs);
  gemm_bt<3><<<g1, blk, 0, stream>>>(xb, wvb, Vtb, nullptr, nullptr, nullptr);

  dim3 g2(32, 64);
  flash_attn<<<g2, blk, 0, stream>>>(Qb, Kb, Vtb, attn);  // attn overwrites xb (x dead)

  convert_bf16<<<n8 / 256, blk, 0, stream>>>(wo, wob, n8);  // wqb slot (wq dead)
  gemm_bt<4><<<g1, blk, 0, stream>>>(attn, wob, nullptr, out, nullptr, nullptr);
}